// Round 1
// baseline (790.934 us; speedup 1.0000x reference)
//
#include <hip/hip_runtime.h>
#include <hip/hip_bf16.h>
#include <cstdint>

// Problem dims
#define N_TOK 8192   // B*T
#define D_IN  1024
#define DFF   4096
#define NE    8

typedef __bf16 bf16x8 __attribute__((ext_vector_type(8)));
typedef float  f32x4  __attribute__((ext_vector_type(4)));

// ---------- helpers ----------
__device__ __forceinline__ unsigned short f2bf(float f) {
  unsigned u = __float_as_uint(f);
  u += 0x7fffu + ((u >> 16) & 1u);   // RNE
  return (unsigned short)(u >> 16);
}

__device__ __forceinline__ void gll16(const void* g, void* l) {
  __builtin_amdgcn_global_load_lds(
      (__attribute__((address_space(1))) void*)g,
      (__attribute__((address_space(3))) void*)l, 16, 0, 0);
}

// ---------- gate: logits (fp64 acc) -> argmax -> bucketize; also x->bf16 ----------
__global__ __launch_bounds__(256) void gate_kernel(
    const float* __restrict__ x, const float* __restrict__ gW,
    const float* __restrict__ gb, unsigned short* __restrict__ xbf,
    int* __restrict__ counts, int* __restrict__ perm) {
  int wave = threadIdx.x >> 6, lane = threadIdx.x & 63;
  int n = blockIdx.x * 4 + wave;
  const float* xr = x + (size_t)n * D_IN;
  double acc[NE];
#pragma unroll
  for (int e = 0; e < NE; ++e) acc[e] = 0.0;
#pragma unroll
  for (int j = 0; j < 16; ++j) {
    int d = j * 64 + lane;
    float v = xr[d];
    xbf[(size_t)n * D_IN + d] = f2bf(v);
    float4 g0 = *(const float4*)(gW + (size_t)d * 8);
    float4 g1 = *(const float4*)(gW + (size_t)d * 8 + 4);
    acc[0] += (double)v * (double)g0.x;
    acc[1] += (double)v * (double)g0.y;
    acc[2] += (double)v * (double)g0.z;
    acc[3] += (double)v * (double)g0.w;
    acc[4] += (double)v * (double)g1.x;
    acc[5] += (double)v * (double)g1.y;
    acc[6] += (double)v * (double)g1.z;
    acc[7] += (double)v * (double)g1.w;
  }
#pragma unroll
  for (int m = 32; m >= 1; m >>= 1) {
#pragma unroll
    for (int e = 0; e < NE; ++e) acc[e] += __shfl_xor(acc[e], m);
  }
  if (lane == 0) {
    float best = (float)acc[0] + gb[0];
    int be = 0;
#pragma unroll
    for (int e = 1; e < NE; ++e) {
      float lv = (float)acc[e] + gb[e];
      if (lv > best) { best = lv; be = e; }   // strict > => first max (jnp.argmax)
    }
    int pos = atomicAdd(&counts[be], 1);
    perm[be * N_TOK + pos] = n;
  }
}

// ---------- plan: offsets + tile worklist ----------
__global__ void plan_kernel(int* __restrict__ hdr, int* __restrict__ tile_e,
                            int* __restrict__ tile_m) {
  if (threadIdx.x != 0 || blockIdx.x != 0) return;
  int off = 0;
  for (int e = 0; e < NE; ++e) { hdr[8 + e] = off; off += hdr[e]; }
  hdr[16] = off;
  int nt = 0;
  for (int e = 0; e < NE; ++e)
    for (int m0 = 0; m0 < hdr[e]; m0 += 128) { tile_e[nt] = e; tile_m[nt] = m0; ++nt; }
  hdr[17] = nt;
}

// ---------- transpose + fp32->bf16: src[e][R][C] -> dst[e][C][R] ----------
__global__ __launch_bounds__(256) void transpose_cvt(
    const float* __restrict__ src, unsigned short* __restrict__ dst,
    int R, int C, int tiles_r, int tiles_c) {
  __shared__ unsigned short tile[64][68];
  int tpe = tiles_r * tiles_c;
  int e = blockIdx.x / tpe;
  int t = blockIdx.x % tpe;
  int r0 = (t / tiles_c) * 64, c0 = (t % tiles_c) * 64;
  const float* s = src + (size_t)e * R * C;
  unsigned short* dp = dst + (size_t)e * R * C;
  int tr = threadIdx.x >> 4, tc = (threadIdx.x & 15) * 4;
#pragma unroll
  for (int p = 0; p < 4; ++p) {
    int row = r0 + tr + p * 16;
    const float4 v = *(const float4*)(s + (size_t)row * C + c0 + tc);
    tile[tc + 0][tr + p * 16] = f2bf(v.x);
    tile[tc + 1][tr + p * 16] = f2bf(v.y);
    tile[tc + 2][tr + p * 16] = f2bf(v.z);
    tile[tc + 3][tr + p * 16] = f2bf(v.w);
  }
  __syncthreads();
#pragma unroll
  for (int p = 0; p < 4; ++p) {
    int cr = tr + p * 16;
    ushort4 o;
    o.x = tile[cr][tc + 0];
    o.y = tile[cr][tc + 1];
    o.z = tile[cr][tc + 2];
    o.w = tile[cr][tc + 3];
    *(ushort4*)(dp + (size_t)(c0 + cr) * R + r0 + tc) = o;
  }
}

// ---------- GEMM1: H = gelu(Xg @ W1 + b1), bf16 out, row-gathered A ----------
__global__ __launch_bounds__(256) void gemm1(
    const unsigned short* __restrict__ xbf, const unsigned short* __restrict__ w1t,
    const float* __restrict__ b1, const int* __restrict__ hdr,
    const int* __restrict__ tile_e, const int* __restrict__ tile_m,
    const int* __restrict__ perm, unsigned short* __restrict__ H) {
  int wi = blockIdx.x >> 5;            // 32 n-tiles (DFF/128)
  if (wi >= hdr[17]) return;
  int nt = blockIdx.x & 31;
  int e = tile_e[wi];
  int m0 = tile_m[wi];
  int Me = hdr[e];
  int hbase = hdr[8 + e];
  int n0 = nt * 128;

  __shared__ __align__(16) char Asm[8192];
  __shared__ __align__(16) char Bsm[8192];

  int tid = threadIdx.x, wave = tid >> 6, lane = tid & 63;
  int wm = wave >> 1, wn = wave & 1;
  int kq = lane >> 4, m = lane & 15;

  const char* aptr[2];
  const char* bptr[2];
  char* alds[2];
  char* blds[2];
#pragma unroll
  for (int s = 0; s < 2; ++s) {
    int g = wave * 2 + s;
    int r = m0 + g * 16 + m;
    if (r >= Me) r = Me - 1;
    int token = perm[e * N_TOK + r];
    aptr[s] = (const char*)xbf + (size_t)token * (D_IN * 2) + kq * 16;
    alds[s] = Asm + g * 1024 + lane * 16;
    int f = n0 + g * 16 + m;
    bptr[s] = (const char*)w1t + ((size_t)e * DFF + f) * (D_IN * 2) + kq * 16;
    blds[s] = Bsm + g * 1024 + lane * 16;
  }

  f32x4 acc[4][4];
#pragma unroll
  for (int i = 0; i < 4; ++i)
#pragma unroll
    for (int j = 0; j < 4; ++j) { f32x4 z = {0.f, 0.f, 0.f, 0.f}; acc[i][j] = z; }

  for (int kk = 0; kk < D_IN / 32; ++kk) {
    gll16(aptr[0] + kk * 64, alds[0]);
    gll16(aptr[1] + kk * 64, alds[1]);
    gll16(bptr[0] + kk * 64, blds[0]);
    gll16(bptr[1] + kk * 64, blds[1]);
    __syncthreads();
    bf16x8 af[4], bfv[4];
#pragma unroll
    for (int i = 0; i < 4; ++i)
      af[i] = *(const bf16x8*)(Asm + (wm * 4 + i) * 1024 + lane * 16);
#pragma unroll
    for (int j = 0; j < 4; ++j)
      bfv[j] = *(const bf16x8*)(Bsm + (wn * 4 + j) * 1024 + lane * 16);
#pragma unroll
    for (int i = 0; i < 4; ++i)
#pragma unroll
      for (int j = 0; j < 4; ++j)
        acc[i][j] = __builtin_amdgcn_mfma_f32_16x16x32_bf16(af[i], bfv[j], acc[i][j], 0, 0, 0);
    __syncthreads();
  }

  int quad = lane >> 4, col_l = lane & 15;
#pragma unroll
  for (int i = 0; i < 4; ++i) {
    int rbase = m0 + wm * 64 + i * 16 + quad * 4;
#pragma unroll
    for (int j = 0; j < 4; ++j) {
      int f = n0 + wn * 64 + j * 16 + col_l;
      float bb = b1[(size_t)e * DFF + f];
#pragma unroll
      for (int r = 0; r < 4; ++r) {
        int rr = rbase + r;
        if (rr < Me) {
          float v = acc[i][j][r] + bb;
          v = 0.5f * v * (1.0f + erff(v * 0.70710678118654752f));  // exact gelu
          H[(size_t)(hbase + rr) * DFF + f] = f2bf(v);
        }
      }
    }
  }
}

// ---------- GEMM2: out[token] = H @ W2 + b2, scattered fp32 ----------
__global__ __launch_bounds__(256) void gemm2(
    const unsigned short* __restrict__ H, const unsigned short* __restrict__ w2t,
    const float* __restrict__ b2, const int* __restrict__ hdr,
    const int* __restrict__ tile_e, const int* __restrict__ tile_m,
    const int* __restrict__ perm, float* __restrict__ out) {
  int wi = blockIdx.x >> 3;            // 8 n-tiles (D/128)
  if (wi >= hdr[17]) return;
  int nt = blockIdx.x & 7;
  int e = tile_e[wi];
  int m0 = tile_m[wi];
  int Me = hdr[e];
  int hbase = hdr[8 + e];
  int n0 = nt * 128;

  __shared__ __align__(16) char Asm[8192];
  __shared__ __align__(16) char Bsm[8192];

  int tid = threadIdx.x, wave = tid >> 6, lane = tid & 63;
  int wm = wave >> 1, wn = wave & 1;
  int kq = lane >> 4, m = lane & 15;

  const char* aptr[2];
  const char* bptr[2];
  char* alds[2];
  char* blds[2];
#pragma unroll
  for (int s = 0; s < 2; ++s) {
    int g = wave * 2 + s;
    int r = m0 + g * 16 + m;
    if (r >= Me) r = Me - 1;
    aptr[s] = (const char*)H + (size_t)(hbase + r) * (DFF * 2) + kq * 16;
    alds[s] = Asm + g * 1024 + lane * 16;
    int d = n0 + g * 16 + m;
    bptr[s] = (const char*)w2t + ((size_t)e * D_IN + d) * (DFF * 2) + kq * 16;
    blds[s] = Bsm + g * 1024 + lane * 16;
  }

  f32x4 acc[4][4];
#pragma unroll
  for (int i = 0; i < 4; ++i)
#pragma unroll
    for (int j = 0; j < 4; ++j) { f32x4 z = {0.f, 0.f, 0.f, 0.f}; acc[i][j] = z; }

  for (int kk = 0; kk < DFF / 32; ++kk) {
    gll16(aptr[0] + kk * 64, alds[0]);
    gll16(aptr[1] + kk * 64, alds[1]);
    gll16(bptr[0] + kk * 64, blds[0]);
    gll16(bptr[1] + kk * 64, blds[1]);
    __syncthreads();
    bf16x8 af[4], bfv[4];
#pragma unroll
    for (int i = 0; i < 4; ++i)
      af[i] = *(const bf16x8*)(Asm + (wm * 4 + i) * 1024 + lane * 16);
#pragma unroll
    for (int j = 0; j < 4; ++j)
      bfv[j] = *(const bf16x8*)(Bsm + (wn * 4 + j) * 1024 + lane * 16);
#pragma unroll
    for (int i = 0; i < 4; ++i)
#pragma unroll
      for (int j = 0; j < 4; ++j)
        acc[i][j] = __builtin_amdgcn_mfma_f32_16x16x32_bf16(af[i], bfv[j], acc[i][j], 0, 0, 0);
    __syncthreads();
  }

  int quad = lane >> 4, col_l = lane & 15;
#pragma unroll
  for (int i = 0; i < 4; ++i) {
    int rbase = m0 + wm * 64 + i * 16 + quad * 4;
#pragma unroll
    for (int j = 0; j < 4; ++j) {
      int col = n0 + wn * 64 + j * 16 + col_l;
      float bb = b2[(size_t)e * D_IN + col];
#pragma unroll
      for (int r = 0; r < 4; ++r) {
        int rr = rbase + r;
        if (rr < Me) {
          int token = perm[e * N_TOK + rr];
          out[(size_t)token * D_IN + col] = acc[i][j][r] + bb;
        }
      }
    }
  }
}

// ---------- launch ----------
extern "C" void kernel_launch(void* const* d_in, const int* in_sizes, int n_in,
                              void* d_out, int out_size, void* d_ws, size_t ws_size,
                              hipStream_t stream) {
  const float* x  = (const float*)d_in[0];
  const float* gW = (const float*)d_in[1];
  const float* gb = (const float*)d_in[2];
  const float* W1 = (const float*)d_in[3];
  const float* b1 = (const float*)d_in[4];
  const float* W2 = (const float*)d_in[5];
  const float* b2 = (const float*)d_in[6];
  float* out = (float*)d_out;

  char* ws = (char*)d_ws;
  int* hdr    = (int*)ws;                    // [0..7] counts, [8..16] offsets, [17] numTiles
  int* tile_e = (int*)(ws + 256);
  int* tile_m = (int*)(ws + 1024);
  int* perm   = (int*)(ws + 4096);                       // NE*N_TOK ints = 256KB
  unsigned short* xbf = (unsigned short*)(ws + 266240);  // 16 MB
  unsigned short* WT  = (unsigned short*)(ws + 17043456); // 64 MB (W1T, then W2T)
  unsigned short* H   = (unsigned short*)(ws + 84152320); // 64 MB
  // total ws use: ~151.3 MB

  hipMemsetAsync(hdr, 0, 256, stream);
  gate_kernel<<<N_TOK / 4, 256, 0, stream>>>(x, gW, gb, xbf, hdr, perm);
  plan_kernel<<<1, 64, 0, stream>>>(hdr, tile_e, tile_m);
  transpose_cvt<<<NE * (D_IN / 64) * (DFF / 64), 256, 0, stream>>>(W1, WT, D_IN, DFF,
                                                                   D_IN / 64, DFF / 64);
  gemm1<<<71 * 32, 256, 0, stream>>>(xbf, WT, b1, hdr, tile_e, tile_m, perm, H);
  transpose_cvt<<<NE * (DFF / 64) * (D_IN / 64), 256, 0, stream>>>(W2, WT, DFF, D_IN,
                                                                   DFF / 64, D_IN / 64);
  gemm2<<<71 * 8, 256, 0, stream>>>(H, WT, b2, hdr, tile_e, tile_m, perm, out);
}